// Round 12
// baseline (257.537 us; speedup 1.0000x reference)
//
#include <hip/hip_runtime.h>
#include <hip/hip_bf16.h>

#define DM 1024
#define DI 2048
#define DS 16
#define DC 4
#define BB 2
#define TT 1024
#define MM (BB*TT)   // 2048 rows
#define CCH 32       // scan chunks
#define LCH 32       // chunk length (TT/CCH)

typedef unsigned short u16;
typedef __attribute__((ext_vector_type(8))) short bf16x8;   // 8 bf16 (4 VGPRs)
typedef __attribute__((ext_vector_type(4))) float f32x4;    // 4 fp32 acc

__device__ __forceinline__ float bu2f(u16 u) {
    union { unsigned int i; float f; } w; w.i = ((unsigned int)u) << 16; return w.f;
}
__device__ __forceinline__ u16 f2bu(float f) {  // round-to-nearest-even bf16
    union { float f; unsigned int u; } w; w.f = f;
    unsigned int r = w.u + 0x7fffu + ((w.u >> 16) & 1u);
    return (u16)(r >> 16);
}

// ======= prep: LayerNorm (blocks 0..MM-1) + weight f32->bf16 (rest) ========
#define F2B_BLOCKS 6144   // (2*DI*DM + DM*DI)/4 float4s / 256 threads
__global__ __launch_bounds__(256) void prep_kernel(const float* __restrict__ x,
                                                   const float* __restrict__ gamma,
                                                   const float* __restrict__ beta,
                                                   u16* __restrict__ xn,
                                                   const float* __restrict__ Wi,
                                                   u16* __restrict__ Wi_b,
                                                   const float* __restrict__ Wo,
                                                   u16* __restrict__ Wo_b) {
    const int tid = threadIdx.x;
    if (blockIdx.x >= MM) {
        // weight conversion: combined range over W_in (n4W) then W_out (n4O)
        const int n4W = 2 * DI * DM / 4;
        int i = (blockIdx.x - MM) * 256 + tid;
        const float* in; u16* out;
        if (i < n4W) { in = Wi; out = Wi_b; }
        else { in = Wo; out = Wo_b; i -= n4W; }
        float4 v = reinterpret_cast<const float4*>(in)[i];
        ushort4 o;
        o.x = f2bu(v.x); o.y = f2bu(v.y); o.z = f2bu(v.z); o.w = f2bu(v.w);
        reinterpret_cast<ushort4*>(out)[i] = o;
        return;
    }
    __shared__ float sbuf[8];
    const int row = blockIdx.x;
    float4 v = reinterpret_cast<const float4*>(x + (size_t)row * DM)[tid];

    float s = v.x + v.y + v.z + v.w;
    #pragma unroll
    for (int off = 32; off; off >>= 1) s += __shfl_down(s, off);
    if ((tid & 63) == 0) sbuf[tid >> 6] = s;
    __syncthreads();
    float mu = (sbuf[0] + sbuf[1] + sbuf[2] + sbuf[3]) * (1.0f / DM);
    __syncthreads();

    float d0 = v.x - mu, d1 = v.y - mu, d2 = v.z - mu, d3 = v.w - mu;
    float q = d0*d0 + d1*d1 + d2*d2 + d3*d3;
    #pragma unroll
    for (int off = 32; off; off >>= 1) q += __shfl_down(q, off);
    if ((tid & 63) == 0) sbuf[tid >> 6] = q;
    __syncthreads();
    float var = (sbuf[0] + sbuf[1] + sbuf[2] + sbuf[3]) * (1.0f / DM);
    float rstd = rsqrtf(var + 1e-5f);

    float4 g = reinterpret_cast<const float4*>(gamma)[tid];
    float4 b = reinterpret_cast<const float4*>(beta)[tid];
    ushort4 o;
    o.x = f2bu(d0 * rstd * g.x + b.x);
    o.y = f2bu(d1 * rstd * g.y + b.y);
    o.z = f2bu(d2 * rstd * g.z + b.z);
    o.w = f2bu(d3 * rstd * g.w + b.w);
    reinterpret_cast<ushort4*>(xn + (size_t)row * DM)[tid] = o;
}

// ========== MFMA GEMMs (NT), double-buffered, small tiles for TLP ==========
__device__ __forceinline__ void gl_lds(const u16* g, u16* lds) {
    __builtin_amdgcn_global_load_lds((const __attribute__((address_space(1))) void*)g,
                                     (__attribute__((address_space(3))) void*)lds,
                                     16, 0, 0);
}

// gemm1: 64(M) x 128(N) tile, 4 waves side-by-side in N (each 64x32).
// grid (32, 32) = 1024 blocks -> 4 blocks/CU.
__global__ __launch_bounds__(256) void gemm1_mfma(const u16* __restrict__ A,
                                                  const u16* __restrict__ B,
                                                  u16* __restrict__ C,
                                                  int M, int N, int K) {
    __shared__ u16 As[2][64 * 32];    // 2 x 4 KB
    __shared__ u16 Bs[2][128 * 32];   // 2 x 8 KB  (24 KB total)
    const int tid  = threadIdx.x;
    const int lane = tid & 63;
    const int w    = tid >> 6;          // wave 0..3
    const int wn   = w * 32;            // wave col offset in tile
    const int m0   = blockIdx.y * 64, n0 = blockIdx.x * 128;

    const int crow = lane >> 2;
    const int ck   = (lane & 3) * 8;
    const u16* aP  = A + (size_t)(m0 + 16 * w + crow) * K + ck;
    const u16* bP0 = B + (size_t)(n0 + 32 * w + crow) * K + ck;
    const u16* bP1 = bP0 + (size_t)16 * K;
    const int la = w * 512, lb0 = (2 * w) * 512, lb1 = (2 * w + 1) * 512;

    const int fr = lane & 15, fq = (lane >> 4) * 8;

    gl_lds(aP, &As[0][la]);
    gl_lds(bP0, &Bs[0][lb0]);
    gl_lds(bP1, &Bs[0][lb1]);
    __syncthreads();

    const int iters = K >> 5;
    f32x4 acc[4][2] = {};
    for (int it = 0; it < iters; it++) {
        const int cur = it & 1;
        const int kn = (it + 1) << 5;
        if (kn < K) {
            const int nb = cur ^ 1;
            gl_lds(aP + kn, &As[nb][la]);
            gl_lds(bP0 + kn, &Bs[nb][lb0]);
            gl_lds(bP1 + kn, &Bs[nb][lb1]);
        }
        bf16x8 af[4], bf[2];
        #pragma unroll
        for (int i = 0; i < 4; i++)
            af[i] = *reinterpret_cast<const bf16x8*>(&As[cur][(i * 16 + fr) * 32 + fq]);
        #pragma unroll
        for (int j = 0; j < 2; j++)
            bf[j] = *reinterpret_cast<const bf16x8*>(&Bs[cur][(wn + j * 16 + fr) * 32 + fq]);
        #pragma unroll
        for (int i = 0; i < 4; i++)
            #pragma unroll
            for (int j = 0; j < 2; j++)
                acc[i][j] = __builtin_amdgcn_mfma_f32_16x16x32_bf16(af[i], bf[j], acc[i][j], 0, 0, 0);
        __syncthreads();
    }

    const int erow = (lane >> 4) * 4, ecol = lane & 15;
    #pragma unroll
    for (int i = 0; i < 4; i++)
        #pragma unroll
        for (int j = 0; j < 2; j++) {
            const int col = n0 + wn + j * 16 + ecol;
            #pragma unroll
            for (int r = 0; r < 4; r++) {
                const int row = m0 + i * 16 + erow + r;
                C[(size_t)row * N + col] = f2bu(acc[i][j][r]);
            }
        }
}

// gemm2: 64 x 64 tile, 4 waves 2x2 (each 32x32), +residual, fp32 out.
// grid (16, 32) = 512 blocks -> 2 blocks/CU.
__global__ __launch_bounds__(256) void gemm2_mfma(const u16* __restrict__ A,
                                                  const u16* __restrict__ B,
                                                  float* __restrict__ C,
                                                  const float* __restrict__ resid,
                                                  int M, int N, int K) {
    __shared__ u16 As[2][64 * 32];    // 2 x 4 KB
    __shared__ u16 Bs[2][64 * 32];    // 2 x 4 KB (16 KB total)
    const int tid  = threadIdx.x;
    const int lane = tid & 63;
    const int w    = tid >> 6;
    const int wm   = (w >> 1) * 32, wn = (w & 1) * 32;
    const int m0   = blockIdx.y * 64, n0 = blockIdx.x * 64;

    const int crow = lane >> 2;
    const int ck   = (lane & 3) * 8;
    const u16* aP = A + (size_t)(m0 + 16 * w + crow) * K + ck;
    const u16* bP = B + (size_t)(n0 + 16 * w + crow) * K + ck;
    const int lw = w * 512;

    const int fr = lane & 15, fq = (lane >> 4) * 8;

    gl_lds(aP, &As[0][lw]);
    gl_lds(bP, &Bs[0][lw]);
    __syncthreads();

    const int iters = K >> 5;
    f32x4 acc[2][2] = {};
    for (int it = 0; it < iters; it++) {
        const int cur = it & 1;
        const int kn = (it + 1) << 5;
        if (kn < K) {
            const int nb = cur ^ 1;
            gl_lds(aP + kn, &As[nb][lw]);
            gl_lds(bP + kn, &Bs[nb][lw]);
        }
        bf16x8 af[2], bf[2];
        #pragma unroll
        for (int i = 0; i < 2; i++)
            af[i] = *reinterpret_cast<const bf16x8*>(&As[cur][(wm + i * 16 + fr) * 32 + fq]);
        #pragma unroll
        for (int j = 0; j < 2; j++)
            bf[j] = *reinterpret_cast<const bf16x8*>(&Bs[cur][(wn + j * 16 + fr) * 32 + fq]);
        #pragma unroll
        for (int i = 0; i < 2; i++)
            #pragma unroll
            for (int j = 0; j < 2; j++)
                acc[i][j] = __builtin_amdgcn_mfma_f32_16x16x32_bf16(af[i], bf[j], acc[i][j], 0, 0, 0);
        __syncthreads();
    }

    const int erow = (lane >> 4) * 4, ecol = lane & 15;
    #pragma unroll
    for (int i = 0; i < 2; i++)
        #pragma unroll
        for (int j = 0; j < 2; j++) {
            const int col = n0 + wn + j * 16 + ecol;
            #pragma unroll
            for (int r = 0; r < 4; r++) {
                const int row = m0 + wm + i * 16 + erow + r;
                C[(size_t)row * N + col] = acc[i][j][r] + resid[(size_t)row * N + col];
            }
        }
}

// ====== fused conv(k=4)+SiLU+ssm projection: block = 4 rows of (b,t) =======
// Computes xc for its 4 rows from xz (causal taps, same math as before),
// stores xc (bf16, for the scan) + keeps fp32 in LDS, then projects onto
// W_x (33 x DI) with per-wave n-ownership + shuffle reduce.
__global__ __launch_bounds__(256) void convproj_kernel(const u16* __restrict__ xz,
                                                       const float* __restrict__ cw,
                                                       const float* __restrict__ cb,
                                                       const float* __restrict__ Wx,
                                                       u16* __restrict__ xc,
                                                       float* __restrict__ ssm) {
    __shared__ float xs[4][DI];      // 32 KB
    const int tid = threadIdx.x;
    const int m0 = blockIdx.x * 4;

    #pragma unroll 8
    for (int i = 0; i < 32; i++) {
        const int e = i * 256 + tid;           // [0, 8192)
        const int r = e >> 11, d = e & (DI - 1);
        const int m = m0 + r;
        const int t = m & (TT - 1);
        float acc = cb[d];
        #pragma unroll
        for (int k = 0; k < DC; k++) {
            int tt = t + k - (DC - 1);
            if (tt >= 0)
                acc += bu2f(xz[(size_t)(m + k - (DC - 1)) * (2 * DI) + d]) * cw[d * DC + k];
        }
        float sv = acc / (1.0f + __expf(-acc));
        xs[r][d] = sv;
        xc[(size_t)m * DI + d] = f2bu(sv);
    }
    __syncthreads();

    const int w = tid >> 6, lane = tid & 63;
    for (int n = w; n < 2 * DS + 1; n += 4) {
        const float* wr = Wx + (size_t)n * DI;
        float a0 = 0.f, a1 = 0.f, a2 = 0.f, a3 = 0.f;
        #pragma unroll 4
        for (int i = 0; i < DI / 64; i++) {
            float wv = wr[i * 64 + lane];
            a0 += wv * xs[0][i * 64 + lane];
            a1 += wv * xs[1][i * 64 + lane];
            a2 += wv * xs[2][i * 64 + lane];
            a3 += wv * xs[3][i * 64 + lane];
        }
        #pragma unroll
        for (int off = 32; off; off >>= 1) {
            a0 += __shfl_down(a0, off);
            a1 += __shfl_down(a1, off);
            a2 += __shfl_down(a2, off);
            a3 += __shfl_down(a3, off);
        }
        if (lane == 0) {
            ssm[(size_t)(m0 + 0) * 33 + n] = a0;
            ssm[(size_t)(m0 + 1) * 33 + n] = a1;
            ssm[(size_t)(m0 + 2) * 33 + n] = a2;
            ssm[(size_t)(m0 + 3) * 33 + n] = a3;
        }
    }
}

// ======================= Chunked selective scan =============================
__global__ __launch_bounds__(256) void scan_part1(const float* __restrict__ ssm,
                                                  const u16* __restrict__ xcy,
                                                  const float* __restrict__ w_dt,
                                                  const float* __restrict__ b_dt,
                                                  const float* __restrict__ A_log,
                                                  float* __restrict__ F,
                                                  float* __restrict__ Sdt) {
    __shared__ float sm[LCH * 33];                 // 4224 B
    __shared__ u16 xls[LCH * 256];                 // 16 KB
    const int tid = threadIdx.x;
    const int dt8 = blockIdx.x & 7;                // d-tile (DI/256 = 8)
    const int bc  = blockIdx.x >> 3;               // 0..63
    const int c   = bc & (CCH - 1);
    const int b   = bc >> 5;                       // log2(CCH)=5
    const int d   = dt8 * 256 + tid;

    const int base = ((b * TT) + c * LCH) * 33;
    for (int i = tid; i < LCH * 33; i += 256) sm[i] = ssm[base + i];
    const u16* xg = xcy + (size_t)(b * TT + c * LCH) * DI + dt8 * 256;
    for (int i = tid; i < LCH * 128; i += 256) {   // uint = 2 bf16
        int t = i >> 7, dp = i & 127;
        unsigned int v = *reinterpret_cast<const unsigned int*>(xg + (size_t)t * DI + dp * 2);
        *reinterpret_cast<unsigned int*>(&xls[t * 256 + dp * 2]) = v;
    }
    __syncthreads();

    float A[DS], h[DS];
    #pragma unroll
    for (int n = 0; n < DS; n++) { A[n] = -__expf(A_log[d * DS + n]); h[n] = 0.f; }
    const float wdt = w_dt[d], bdt = b_dt[d];
    float sdt = 0.f;

    for (int t = 0; t < LCH; t++) {
        const float* sp = &sm[t * 33];
        float pre = sp[0] * wdt + bdt;
        float dtv = (pre > 20.f) ? pre : __logf(1.f + __expf(pre));
        sdt += dtv;
        float xv = bu2f(xls[t * 256 + tid]);
        float u = dtv * xv;
        #pragma unroll
        for (int n = 0; n < DS; n++) h[n] = __expf(dtv * A[n]) * h[n] + u * sp[1 + n];
    }
    const size_t fo = ((size_t)(b * CCH + c) * DI + d) * DS;
    #pragma unroll
    for (int n = 0; n < DS; n++) F[fo + n] = h[n];
    Sdt[(b * CCH + c) * DI + d] = sdt;
}

// In-place: on exit F[c] holds the CARRY-IN state for chunk c.
__global__ __launch_bounds__(256) void scan_combine(float* __restrict__ F,
                                                    const float* __restrict__ Sdt,
                                                    const float* __restrict__ A_log) {
    const int g = blockIdx.x * 256 + threadIdx.x;  // B*DI*DS = 65536
    const int n = g & (DS - 1);
    const int d = (g >> 4) & (DI - 1);
    const int b = g >> 15;
    const float A = -__expf(A_log[d * DS + n]);
    float h = 0.f;
    for (int c = 0; c < CCH; c++) {
        const size_t o = ((size_t)(b * CCH + c) * DI + d) * DS + n;
        float f = F[o];
        float q = __expf(Sdt[(b * CCH + c) * DI + d] * A);
        float hn = q * h + f;
        F[o] = h;                                  // carry-in for chunk c
        h = hn;
    }
}

__global__ __launch_bounds__(256) void scan_part2(const float* __restrict__ ssm,
                                                  const u16* __restrict__ xz,
                                                  u16* __restrict__ xcy,
                                                  const float* __restrict__ w_dt,
                                                  const float* __restrict__ b_dt,
                                                  const float* __restrict__ A_log,
                                                  const float* __restrict__ Dp,
                                                  const float* __restrict__ Hin) {
    __shared__ float sm[LCH * 33];
    __shared__ u16 xls[LCH * 256];
    const int tid = threadIdx.x;
    const int dt8 = blockIdx.x & 7;
    const int bc  = blockIdx.x >> 3;
    const int c   = bc & (CCH - 1);
    const int b   = bc >> 5;
    const int d   = dt8 * 256 + tid;

    const int base = ((b * TT) + c * LCH) * 33;
    for (int i = tid; i < LCH * 33; i += 256) sm[i] = ssm[base + i];
    const u16* xg = xcy + (size_t)(b * TT + c * LCH) * DI + dt8 * 256;
    for (int i = tid; i < LCH * 128; i += 256) {
        int t = i >> 7, dp = i & 127;
        unsigned int v = *reinterpret_cast<const unsigned int*>(xg + (size_t)t * DI + dp * 2);
        *reinterpret_cast<unsigned int*>(&xls[t * 256 + dp * 2]) = v;
    }
    __syncthreads();

    float A[DS], h[DS];
    const size_t ho = ((size_t)(b * CCH + c) * DI + d) * DS;
    #pragma unroll
    for (int n = 0; n < DS; n++) { A[n] = -__expf(A_log[d * DS + n]); h[n] = Hin[ho + n]; }
    const float wdt = w_dt[d], bdt = b_dt[d], Dv = Dp[d];

    for (int t = 0; t < LCH; t++) {
        const float* sp = &sm[t * 33];
        float pre = sp[0] * wdt + bdt;
        float dtv = (pre > 20.f) ? pre : __logf(1.f + __expf(pre));
        const size_t row = (size_t)(b * TT + c * LCH + t);
        float xv = bu2f(xls[t * 256 + tid]);
        float u = dtv * xv;
        float y = 0.f;
        #pragma unroll
        for (int n = 0; n < DS; n++) {
            h[n] = __expf(dtv * A[n]) * h[n] + u * sp[1 + n];
            y += h[n] * sp[17 + n];
        }
        float z = bu2f(xz[row * (2 * DI) + DI + d]);
        float sz = z / (1.0f + __expf(-z));
        xcy[row * DI + d] = f2bu((y + Dv * xv) * sz);   // staged reads done; exclusive owner
    }
}

extern "C" void kernel_launch(void* const* d_in, const int* in_sizes, int n_in,
                              void* d_out, int out_size, void* d_ws, size_t ws_size,
                              hipStream_t stream) {
    // Input-order resolution by in_sizes signature (dict order confirmed).
    int ix, ig, ib, iWin, icw, icb, iWx, iwdt, ibdt, iAl, iD, iWo;
    if (n_in >= 12 && in_sizes[0] == 32768) {
        iAl = 0; iD = 1; iWin = 2; iWo = 3; iWx = 4; ibdt = 5;
        icb = 6; icw = 7; ib = 8; ig = 9; iwdt = 10; ix = 11;
    } else if (n_in >= 12 && in_sizes[0] == 2097152 && in_sizes[1] == 2048 && in_sizes[2] == 32768) {
        iWo = 0; iD = 1; iAl = 2; ibdt = 3; iwdt = 4; iWx = 5;
        icb = 6; icw = 7; iWin = 8; ib = 9; ig = 10; ix = 11;
    } else {
        ix = 0; ig = 1; ib = 2; iWin = 3; icw = 4; icb = 5;
        iWx = 6; iwdt = 7; ibdt = 8; iAl = 9; iD = 10; iWo = 11;
    }

    const float* x       = (const float*)d_in[ix];
    const float* ln_g    = (const float*)d_in[ig];
    const float* ln_b    = (const float*)d_in[ib];
    const float* W_in    = (const float*)d_in[iWin];
    const float* conv_w  = (const float*)d_in[icw];
    const float* conv_b  = (const float*)d_in[icb];
    const float* W_x     = (const float*)d_in[iWx];
    const float* w_dt    = (const float*)d_in[iwdt];
    const float* b_dt    = (const float*)d_in[ibdt];
    const float* A_log   = (const float*)d_in[iAl];
    const float* D_param = (const float*)d_in[iD];
    const float* W_out   = (const float*)d_in[iWo];
    float* out = (float*)d_out;   // fp32 output (verified R5)

    // Workspace layout (~49 MB):
    float* ssm  = (float*)d_ws;                     // MM*33 fp32
    u16*   xn   = (u16*)(ssm + (size_t)MM * 33);    // MM*DM bf16
    u16*   xz   = xn + (size_t)MM * DM;             // MM*2*DI bf16
    u16*   xcy  = xz + (size_t)MM * 2 * DI;         // MM*DI bf16 (xc, then y)
    float* F    = (float*)(xcy + (size_t)MM * DI);  // B*CCH*DI*DS fp32 (F, then Hin in place)
    float* Sdt  = F + (size_t)BB * CCH * DI * DS;   // B*CCH*DI fp32
    u16*   Wi_b = (u16*)(Sdt + (size_t)BB * CCH * DI);      // 2*DI*DM bf16
    u16*   Wo_b = Wi_b + (size_t)2 * DI * DM;               // DM*DI bf16

    // LN + both weight conversions in ONE launch
    prep_kernel<<<MM + F2B_BLOCKS, 256, 0, stream>>>(x, ln_g, ln_b, xn, W_in, Wi_b, W_out, Wo_b);

    // xz = xn @ W_in.T   (M=2048, N=4096, K=1024): 64x128 tiles, 1024 blocks
    gemm1_mfma<<<dim3(4096 / 128, MM / 64), 256, 0, stream>>>(xn, Wi_b, xz, MM, 2 * DI, DM);

    // conv+SiLU+projection fused (writes xc for the scan + ssm)
    convproj_kernel<<<MM / 4, 256, 0, stream>>>(xz, conv_w, conv_b, W_x, xcy, ssm);

    // chunked scan: part1 -> combine(in place) -> part2(+gate)
    scan_part1<<<BB * CCH * (DI / 256), 256, 0, stream>>>(ssm, xcy, w_dt, b_dt, A_log, F, Sdt);
    scan_combine<<<(BB * DI * DS) / 256, 256, 0, stream>>>(F, Sdt, A_log);
    scan_part2<<<BB * CCH * (DI / 256), 256, 0, stream>>>(ssm, xz, xcy, w_dt, b_dt, A_log, D_param, F);

    // out = x + y @ W_out.T   (M=2048, N=1024, K=2048): 64x64 tiles, 512 blocks
    gemm2_mfma<<<dim3(1024 / 64, MM / 64), 256, 0, stream>>>(xcy, Wo_b, out, x, MM, DM, DI);
}

// Round 13
// 247.396 us; speedup vs baseline: 1.0410x; 1.0410x over previous
//
#include <hip/hip_runtime.h>
#include <hip/hip_bf16.h>

#define DM 1024
#define DI 2048
#define DS 16
#define DC 4
#define BB 2
#define TT 1024
#define MM (BB*TT)   // 2048 rows
#define CCH 32       // scan chunks
#define LCH 32       // chunk length (TT/CCH)

typedef unsigned short u16;
typedef __attribute__((ext_vector_type(8))) short bf16x8;   // 8 bf16 (4 VGPRs)
typedef __attribute__((ext_vector_type(4))) float f32x4;    // 4 fp32 acc

__device__ __forceinline__ float bu2f(u16 u) {
    union { unsigned int i; float f; } w; w.i = ((unsigned int)u) << 16; return w.f;
}
__device__ __forceinline__ u16 f2bu(float f) {  // round-to-nearest-even bf16
    union { float f; unsigned int u; } w; w.f = f;
    unsigned int r = w.u + 0x7fffu + ((w.u >> 16) & 1u);
    return (u16)(r >> 16);
}

// ======= prep: LayerNorm (blocks 0..MM-1) + weight f32->bf16 (rest) ========
#define F2B_BLOCKS 6144   // (2*DI*DM + DM*DI)/4 float4s / 256 threads
__global__ __launch_bounds__(256) void prep_kernel(const float* __restrict__ x,
                                                   const float* __restrict__ gamma,
                                                   const float* __restrict__ beta,
                                                   u16* __restrict__ xn,
                                                   const float* __restrict__ Wi,
                                                   u16* __restrict__ Wi_b,
                                                   const float* __restrict__ Wo,
                                                   u16* __restrict__ Wo_b) {
    const int tid = threadIdx.x;
    if (blockIdx.x >= MM) {
        const int n4W = 2 * DI * DM / 4;
        int i = (blockIdx.x - MM) * 256 + tid;
        const float* in; u16* out;
        if (i < n4W) { in = Wi; out = Wi_b; }
        else { in = Wo; out = Wo_b; i -= n4W; }
        float4 v = reinterpret_cast<const float4*>(in)[i];
        ushort4 o;
        o.x = f2bu(v.x); o.y = f2bu(v.y); o.z = f2bu(v.z); o.w = f2bu(v.w);
        reinterpret_cast<ushort4*>(out)[i] = o;
        return;
    }
    __shared__ float sbuf[8];
    const int row = blockIdx.x;
    float4 v = reinterpret_cast<const float4*>(x + (size_t)row * DM)[tid];

    float s = v.x + v.y + v.z + v.w;
    #pragma unroll
    for (int off = 32; off; off >>= 1) s += __shfl_down(s, off);
    if ((tid & 63) == 0) sbuf[tid >> 6] = s;
    __syncthreads();
    float mu = (sbuf[0] + sbuf[1] + sbuf[2] + sbuf[3]) * (1.0f / DM);
    __syncthreads();

    float d0 = v.x - mu, d1 = v.y - mu, d2 = v.z - mu, d3 = v.w - mu;
    float q = d0*d0 + d1*d1 + d2*d2 + d3*d3;
    #pragma unroll
    for (int off = 32; off; off >>= 1) q += __shfl_down(q, off);
    if ((tid & 63) == 0) sbuf[tid >> 6] = q;
    __syncthreads();
    float var = (sbuf[0] + sbuf[1] + sbuf[2] + sbuf[3]) * (1.0f / DM);
    float rstd = rsqrtf(var + 1e-5f);

    float4 g = reinterpret_cast<const float4*>(gamma)[tid];
    float4 b = reinterpret_cast<const float4*>(beta)[tid];
    ushort4 o;
    o.x = f2bu(d0 * rstd * g.x + b.x);
    o.y = f2bu(d1 * rstd * g.y + b.y);
    o.z = f2bu(d2 * rstd * g.z + b.z);
    o.w = f2bu(d3 * rstd * g.w + b.w);
    reinterpret_cast<ushort4*>(xn + (size_t)row * DM)[tid] = o;
}

// ========== MFMA GEMMs (NT), double-buffered, small tiles for TLP ==========
__device__ __forceinline__ void gl_lds(const u16* g, u16* lds) {
    __builtin_amdgcn_global_load_lds((const __attribute__((address_space(1))) void*)g,
                                     (__attribute__((address_space(3))) void*)lds,
                                     16, 0, 0);
}

// gemm1: 64(M) x 128(N) tile, 4 waves side-by-side in N (each 64x32).
// grid (32, 32) = 1024 blocks -> 4 blocks/CU.
__global__ __launch_bounds__(256) void gemm1_mfma(const u16* __restrict__ A,
                                                  const u16* __restrict__ B,
                                                  u16* __restrict__ C,
                                                  int M, int N, int K) {
    __shared__ u16 As[2][64 * 32];    // 2 x 4 KB
    __shared__ u16 Bs[2][128 * 32];   // 2 x 8 KB  (24 KB total)
    const int tid  = threadIdx.x;
    const int lane = tid & 63;
    const int w    = tid >> 6;          // wave 0..3
    const int wn   = w * 32;            // wave col offset in tile
    const int m0   = blockIdx.y * 64, n0 = blockIdx.x * 128;

    const int crow = lane >> 2;
    const int ck   = (lane & 3) * 8;
    const u16* aP  = A + (size_t)(m0 + 16 * w + crow) * K + ck;
    const u16* bP0 = B + (size_t)(n0 + 32 * w + crow) * K + ck;
    const u16* bP1 = bP0 + (size_t)16 * K;
    const int la = w * 512, lb0 = (2 * w) * 512, lb1 = (2 * w + 1) * 512;

    const int fr = lane & 15, fq = (lane >> 4) * 8;

    gl_lds(aP, &As[0][la]);
    gl_lds(bP0, &Bs[0][lb0]);
    gl_lds(bP1, &Bs[0][lb1]);
    __syncthreads();

    const int iters = K >> 5;
    f32x4 acc[4][2] = {};
    for (int it = 0; it < iters; it++) {
        const int cur = it & 1;
        const int kn = (it + 1) << 5;
        if (kn < K) {
            const int nb = cur ^ 1;
            gl_lds(aP + kn, &As[nb][la]);
            gl_lds(bP0 + kn, &Bs[nb][lb0]);
            gl_lds(bP1 + kn, &Bs[nb][lb1]);
        }
        bf16x8 af[4], bf[2];
        #pragma unroll
        for (int i = 0; i < 4; i++)
            af[i] = *reinterpret_cast<const bf16x8*>(&As[cur][(i * 16 + fr) * 32 + fq]);
        #pragma unroll
        for (int j = 0; j < 2; j++)
            bf[j] = *reinterpret_cast<const bf16x8*>(&Bs[cur][(wn + j * 16 + fr) * 32 + fq]);
        #pragma unroll
        for (int i = 0; i < 4; i++)
            #pragma unroll
            for (int j = 0; j < 2; j++)
                acc[i][j] = __builtin_amdgcn_mfma_f32_16x16x32_bf16(af[i], bf[j], acc[i][j], 0, 0, 0);
        __syncthreads();
    }

    const int erow = (lane >> 4) * 4, ecol = lane & 15;
    #pragma unroll
    for (int i = 0; i < 4; i++)
        #pragma unroll
        for (int j = 0; j < 2; j++) {
            const int col = n0 + wn + j * 16 + ecol;
            #pragma unroll
            for (int r = 0; r < 4; r++) {
                const int row = m0 + i * 16 + erow + r;
                C[(size_t)row * N + col] = f2bu(acc[i][j][r]);
            }
        }
}

// gemm2: 64 x 64 tile, 4 waves 2x2 (each 32x32), +residual, fp32 out.
// grid (16, 32) = 512 blocks -> 2 blocks/CU.
__global__ __launch_bounds__(256) void gemm2_mfma(const u16* __restrict__ A,
                                                  const u16* __restrict__ B,
                                                  float* __restrict__ C,
                                                  const float* __restrict__ resid,
                                                  int M, int N, int K) {
    __shared__ u16 As[2][64 * 32];    // 2 x 4 KB
    __shared__ u16 Bs[2][64 * 32];    // 2 x 4 KB (16 KB total)
    const int tid  = threadIdx.x;
    const int lane = tid & 63;
    const int w    = tid >> 6;
    const int wm   = (w >> 1) * 32, wn = (w & 1) * 32;
    const int m0   = blockIdx.y * 64, n0 = blockIdx.x * 64;

    const int crow = lane >> 2;
    const int ck   = (lane & 3) * 8;
    const u16* aP = A + (size_t)(m0 + 16 * w + crow) * K + ck;
    const u16* bP = B + (size_t)(n0 + 16 * w + crow) * K + ck;
    const int lw = w * 512;

    const int fr = lane & 15, fq = (lane >> 4) * 8;

    gl_lds(aP, &As[0][lw]);
    gl_lds(bP, &Bs[0][lw]);
    __syncthreads();

    const int iters = K >> 5;
    f32x4 acc[2][2] = {};
    for (int it = 0; it < iters; it++) {
        const int cur = it & 1;
        const int kn = (it + 1) << 5;
        if (kn < K) {
            const int nb = cur ^ 1;
            gl_lds(aP + kn, &As[nb][lw]);
            gl_lds(bP + kn, &Bs[nb][lw]);
        }
        bf16x8 af[2], bf[2];
        #pragma unroll
        for (int i = 0; i < 2; i++)
            af[i] = *reinterpret_cast<const bf16x8*>(&As[cur][(wm + i * 16 + fr) * 32 + fq]);
        #pragma unroll
        for (int j = 0; j < 2; j++)
            bf[j] = *reinterpret_cast<const bf16x8*>(&Bs[cur][(wn + j * 16 + fr) * 32 + fq]);
        #pragma unroll
        for (int i = 0; i < 2; i++)
            #pragma unroll
            for (int j = 0; j < 2; j++)
                acc[i][j] = __builtin_amdgcn_mfma_f32_16x16x32_bf16(af[i], bf[j], acc[i][j], 0, 0, 0);
        __syncthreads();
    }

    const int erow = (lane >> 4) * 4, ecol = lane & 15;
    #pragma unroll
    for (int i = 0; i < 2; i++)
        #pragma unroll
        for (int j = 0; j < 2; j++) {
            const int col = n0 + wn + j * 16 + ecol;
            #pragma unroll
            for (int r = 0; r < 4; r++) {
                const int row = m0 + wm + i * 16 + erow + r;
                C[(size_t)row * N + col] = acc[i][j][r] + resid[(size_t)row * N + col];
            }
        }
}

// ---------------- Depthwise causal conv (k=4) + SiLU (16k blocks) ----------
__global__ __launch_bounds__(256) void conv_silu_kernel(const u16* __restrict__ xz,
                                                        const float* __restrict__ cw,
                                                        const float* __restrict__ cb,
                                                        u16* __restrict__ xc) {
    const int idx = blockIdx.x * 256 + threadIdx.x;   // MM*DI
    const int d = idx & (DI - 1);
    const int row = idx >> 11;                        // DI = 2048
    const int t = row & (TT - 1);
    float acc = cb[d];
    #pragma unroll
    for (int k = 0; k < DC; k++) {
        int tt = t + k - (DC - 1);
        if (tt >= 0) acc += bu2f(xz[(size_t)(row + k - (DC - 1)) * (2 * DI) + d]) * cw[d * DC + k];
    }
    float sv = acc / (1.0f + __expf(-acc));  // silu
    xc[idx] = f2bu(sv);
}

// ---------------- ssm_p = xc @ W_x.T  (MM x 33), LDS-staged reduction ------
__global__ __launch_bounds__(256) void ssm_proj_kernel(const u16* __restrict__ xc,
                                                       const float* __restrict__ Wx,
                                                       float* __restrict__ ssm) {
    __shared__ float xs[4][DI];      // 32 KB
    const int tid = threadIdx.x;
    const int m0 = blockIdx.x * 4;

    #pragma unroll
    for (int i = 0; i < 8; i++) {
        int idx4 = tid + i * 256;                        // 0..2047
        ushort4 v = reinterpret_cast<const ushort4*>(xc + (size_t)m0 * DI)[idx4];
        int e = idx4 * 4;                                // element in [0, 8192)
        float4 f = make_float4(bu2f(v.x), bu2f(v.y), bu2f(v.z), bu2f(v.w));
        *reinterpret_cast<float4*>(&xs[e >> 11][e & (DI - 1)]) = f;
    }
    __syncthreads();

    const int w = tid >> 6, lane = tid & 63;
    for (int n = w; n < 2 * DS + 1; n += 4) {
        const float* wr = Wx + (size_t)n * DI;
        float a0 = 0.f, a1 = 0.f, a2 = 0.f, a3 = 0.f;
        #pragma unroll 4
        for (int i = 0; i < DI / 64; i++) {
            float wv = wr[i * 64 + lane];
            a0 += wv * xs[0][i * 64 + lane];
            a1 += wv * xs[1][i * 64 + lane];
            a2 += wv * xs[2][i * 64 + lane];
            a3 += wv * xs[3][i * 64 + lane];
        }
        #pragma unroll
        for (int off = 32; off; off >>= 1) {
            a0 += __shfl_down(a0, off);
            a1 += __shfl_down(a1, off);
            a2 += __shfl_down(a2, off);
            a3 += __shfl_down(a3, off);
        }
        if (lane == 0) {
            ssm[(size_t)(m0 + 0) * 33 + n] = a0;
            ssm[(size_t)(m0 + 1) * 33 + n] = a1;
            ssm[(size_t)(m0 + 2) * 33 + n] = a2;
            ssm[(size_t)(m0 + 3) * 33 + n] = a3;
        }
    }
}

// ======================= Chunked selective scan =============================
__global__ __launch_bounds__(256) void scan_part1(const float* __restrict__ ssm,
                                                  const u16* __restrict__ xcy,
                                                  const float* __restrict__ w_dt,
                                                  const float* __restrict__ b_dt,
                                                  const float* __restrict__ A_log,
                                                  float* __restrict__ F,
                                                  float* __restrict__ Sdt) {
    __shared__ float sm[LCH * 33];                 // 4224 B
    __shared__ u16 xls[LCH * 256];                 // 16 KB
    const int tid = threadIdx.x;
    const int dt8 = blockIdx.x & 7;                // d-tile (DI/256 = 8)
    const int bc  = blockIdx.x >> 3;               // 0..63
    const int c   = bc & (CCH - 1);
    const int b   = bc >> 5;                       // log2(CCH)=5
    const int d   = dt8 * 256 + tid;

    const int base = ((b * TT) + c * LCH) * 33;
    for (int i = tid; i < LCH * 33; i += 256) sm[i] = ssm[base + i];
    const u16* xg = xcy + (size_t)(b * TT + c * LCH) * DI + dt8 * 256;
    for (int i = tid; i < LCH * 128; i += 256) {   // uint = 2 bf16
        int t = i >> 7, dp = i & 127;
        unsigned int v = *reinterpret_cast<const unsigned int*>(xg + (size_t)t * DI + dp * 2);
        *reinterpret_cast<unsigned int*>(&xls[t * 256 + dp * 2]) = v;
    }
    __syncthreads();

    float A[DS], h[DS];
    #pragma unroll
    for (int n = 0; n < DS; n++) { A[n] = -__expf(A_log[d * DS + n]); h[n] = 0.f; }
    const float wdt = w_dt[d], bdt = b_dt[d];
    float sdt = 0.f;

    for (int t = 0; t < LCH; t++) {
        const float* sp = &sm[t * 33];
        float pre = sp[0] * wdt + bdt;
        float dtv = (pre > 20.f) ? pre : __logf(1.f + __expf(pre));
        sdt += dtv;
        float xv = bu2f(xls[t * 256 + tid]);
        float u = dtv * xv;
        #pragma unroll
        for (int n = 0; n < DS; n++) h[n] = __expf(dtv * A[n]) * h[n] + u * sp[1 + n];
    }
    const size_t fo = ((size_t)(b * CCH + c) * DI + d) * DS;
    #pragma unroll
    for (int n = 0; n < DS; n++) F[fo + n] = h[n];
    Sdt[(b * CCH + c) * DI + d] = sdt;
}

// In-place: on exit F[c] holds the CARRY-IN state for chunk c.
__global__ __launch_bounds__(256) void scan_combine(float* __restrict__ F,
                                                    const float* __restrict__ Sdt,
                                                    const float* __restrict__ A_log) {
    const int g = blockIdx.x * 256 + threadIdx.x;  // B*DI*DS = 65536
    const int n = g & (DS - 1);
    const int d = (g >> 4) & (DI - 1);
    const int b = g >> 15;
    const float A = -__expf(A_log[d * DS + n]);
    float h = 0.f;
    for (int c = 0; c < CCH; c++) {
        const size_t o = ((size_t)(b * CCH + c) * DI + d) * DS + n;
        float f = F[o];
        float q = __expf(Sdt[(b * CCH + c) * DI + d] * A);
        float hn = q * h + f;
        F[o] = h;                                  // carry-in for chunk c
        h = hn;
    }
}

__global__ __launch_bounds__(256) void scan_part2(const float* __restrict__ ssm,
                                                  const u16* __restrict__ xz,
                                                  u16* __restrict__ xcy,
                                                  const float* __restrict__ w_dt,
                                                  const float* __restrict__ b_dt,
                                                  const float* __restrict__ A_log,
                                                  const float* __restrict__ Dp,
                                                  const float* __restrict__ Hin) {
    __shared__ float sm[LCH * 33];
    __shared__ u16 xls[LCH * 256];
    const int tid = threadIdx.x;
    const int dt8 = blockIdx.x & 7;
    const int bc  = blockIdx.x >> 3;
    const int c   = bc & (CCH - 1);
    const int b   = bc >> 5;
    const int d   = dt8 * 256 + tid;

    const int base = ((b * TT) + c * LCH) * 33;
    for (int i = tid; i < LCH * 33; i += 256) sm[i] = ssm[base + i];
    const u16* xg = xcy + (size_t)(b * TT + c * LCH) * DI + dt8 * 256;
    for (int i = tid; i < LCH * 128; i += 256) {
        int t = i >> 7, dp = i & 127;
        unsigned int v = *reinterpret_cast<const unsigned int*>(xg + (size_t)t * DI + dp * 2);
        *reinterpret_cast<unsigned int*>(&xls[t * 256 + dp * 2]) = v;
    }
    __syncthreads();

    float A[DS], h[DS];
    const size_t ho = ((size_t)(b * CCH + c) * DI + d) * DS;
    #pragma unroll
    for (int n = 0; n < DS; n++) { A[n] = -__expf(A_log[d * DS + n]); h[n] = Hin[ho + n]; }
    const float wdt = w_dt[d], bdt = b_dt[d], Dv = Dp[d];

    for (int t = 0; t < LCH; t++) {
        const float* sp = &sm[t * 33];
        float pre = sp[0] * wdt + bdt;
        float dtv = (pre > 20.f) ? pre : __logf(1.f + __expf(pre));
        const size_t row = (size_t)(b * TT + c * LCH + t);
        float xv = bu2f(xls[t * 256 + tid]);
        float u = dtv * xv;
        float y = 0.f;
        #pragma unroll
        for (int n = 0; n < DS; n++) {
            h[n] = __expf(dtv * A[n]) * h[n] + u * sp[1 + n];
            y += h[n] * sp[17 + n];
        }
        float z = bu2f(xz[row * (2 * DI) + DI + d]);
        float sz = z / (1.0f + __expf(-z));
        xcy[row * DI + d] = f2bu((y + Dv * xv) * sz);   // staged reads done; exclusive owner
    }
}

extern "C" void kernel_launch(void* const* d_in, const int* in_sizes, int n_in,
                              void* d_out, int out_size, void* d_ws, size_t ws_size,
                              hipStream_t stream) {
    // Input-order resolution by in_sizes signature (dict order confirmed).
    int ix, ig, ib, iWin, icw, icb, iWx, iwdt, ibdt, iAl, iD, iWo;
    if (n_in >= 12 && in_sizes[0] == 32768) {
        iAl = 0; iD = 1; iWin = 2; iWo = 3; iWx = 4; ibdt = 5;
        icb = 6; icw = 7; ib = 8; ig = 9; iwdt = 10; ix = 11;
    } else if (n_in >= 12 && in_sizes[0] == 2097152 && in_sizes[1] == 2048 && in_sizes[2] == 32768) {
        iWo = 0; iD = 1; iAl = 2; ibdt = 3; iwdt = 4; iWx = 5;
        icb = 6; icw = 7; iWin = 8; ib = 9; ig = 10; ix = 11;
    } else {
        ix = 0; ig = 1; ib = 2; iWin = 3; icw = 4; icb = 5;
        iWx = 6; iwdt = 7; ibdt = 8; iAl = 9; iD = 10; iWo = 11;
    }

    const float* x       = (const float*)d_in[ix];
    const float* ln_g    = (const float*)d_in[ig];
    const float* ln_b    = (const float*)d_in[ib];
    const float* W_in    = (const float*)d_in[iWin];
    const float* conv_w  = (const float*)d_in[icw];
    const float* conv_b  = (const float*)d_in[icb];
    const float* W_x     = (const float*)d_in[iWx];
    const float* w_dt    = (const float*)d_in[iwdt];
    const float* b_dt    = (const float*)d_in[ibdt];
    const float* A_log   = (const float*)d_in[iAl];
    const float* D_param = (const float*)d_in[iD];
    const float* W_out   = (const float*)d_in[iWo];
    float* out = (float*)d_out;   // fp32 output (verified R5)

    // Workspace layout (~49 MB):
    float* ssm  = (float*)d_ws;                     // MM*33 fp32
    u16*   xn   = (u16*)(ssm + (size_t)MM * 33);    // MM*DM bf16
    u16*   xz   = xn + (size_t)MM * DM;             // MM*2*DI bf16
    u16*   xcy  = xz + (size_t)MM * 2 * DI;         // MM*DI bf16 (xc, then y)
    float* F    = (float*)(xcy + (size_t)MM * DI);  // B*CCH*DI*DS fp32 (F, then Hin in place)
    float* Sdt  = F + (size_t)BB * CCH * DI * DS;   // B*CCH*DI fp32
    u16*   Wi_b = (u16*)(Sdt + (size_t)BB * CCH * DI);      // 2*DI*DM bf16
    u16*   Wo_b = Wi_b + (size_t)2 * DI * DM;               // DM*DI bf16

    // LN + both weight conversions in ONE launch
    prep_kernel<<<MM + F2B_BLOCKS, 256, 0, stream>>>(x, ln_g, ln_b, xn, W_in, Wi_b, W_out, Wo_b);

    // xz = xn @ W_in.T   (M=2048, N=4096, K=1024): 64x128 tiles, 1024 blocks
    gemm1_mfma<<<dim3(4096 / 128, MM / 64), 256, 0, stream>>>(xn, Wi_b, xz, MM, 2 * DI, DM);

    // conv + SiLU (high-TLP: 16384 blocks — do NOT fuse into low-TLP proj)
    conv_silu_kernel<<<(MM * DI) / 256, 256, 0, stream>>>(xz, conv_w, conv_b, xcy);

    // ssm projection: LDS-staged parallel reduction
    ssm_proj_kernel<<<MM / 4, 256, 0, stream>>>(xcy, W_x, ssm);

    // chunked scan: part1 -> combine(in place) -> part2(+gate)
    scan_part1<<<BB * CCH * (DI / 256), 256, 0, stream>>>(ssm, xcy, w_dt, b_dt, A_log, F, Sdt);
    scan_combine<<<(BB * DI * DS) / 256, 256, 0, stream>>>(F, Sdt, A_log);
    scan_part2<<<BB * CCH * (DI / 256), 256, 0, stream>>>(ssm, xz, xcy, w_dt, b_dt, A_log, D_param, F);

    // out = x + y @ W_out.T   (M=2048, N=1024, K=2048): 64x64 tiles, 512 blocks
    gemm2_mfma<<<dim3(1024 / 64, MM / 64), 256, 0, stream>>>(xcy, Wo_b, out, x, MM, DM, DI);
}